// Round 6
// baseline (1215.864 us; speedup 1.0000x reference)
//
#include <hip/hip_runtime.h>
#include <hip/hip_bf16.h>
#include <hip/hip_fp16.h>
#include <stdint.h>

#define DIM 256
#define NG 8192
#define KDIM 512      // 2*DIM (concat [readout | h])
#define GDIM 1024     // 4*DIM gates
#define N_ITERS 6
#define GPB 16        // graphs per block
#define NBLK (NG / GPB)   // 512 blocks = 2 per CU
#define NTHR 512          // 8 waves
#define GPW 2             // graphs per wave in att

typedef __hip_bfloat16 bf16;
typedef __attribute__((ext_vector_type(8))) short bf16x8;
typedef __attribute__((ext_vector_type(4))) float f32x4;
typedef __attribute__((ext_vector_type(8))) unsigned short u16x8;

// ---------------- helpers --------------
__device__ __forceinline__ float fast_sigmoid(float v) {
    return 1.0f / (1.0f + __expf(-v));
}
__device__ __forceinline__ float fast_tanh(float v) {
    float e = __expf(2.0f * v);
    return (e - 1.0f) / (e + 1.0f);
}
__device__ __forceinline__ unsigned short f2bf(float v) {
    __hip_bfloat16 t = __float2bfloat16(v);
    unsigned short u; __builtin_memcpy(&u, &t, 2); return u;
}
__device__ __forceinline__ unsigned short f2h(float v) {
    __half t = __float2half_rn(v);
    unsigned short u; __builtin_memcpy(&u, &t, 2); return u;
}
__device__ __forceinline__ float h2f(unsigned short u) {
    __half t; __builtin_memcpy(&t, &u, 2);
    return __half2float(t);
}

// Block-local persistent state: A=[readout|h] bf16 (XOR-swizzled rows) + h fp32.
// REAL data: 16KB + 16KB = 32KB. `pad` inflates static LDS to 56KB so the compiler's
// LDS-derived occupancy target is floor(160/56) = 2 blocks/CU = 4 waves/EU, which sets
// the per-wave VGPR budget to 128. Measured across R1-R5: the allocator budgets VGPRs
// from LDS-permitted occupancy (64KB->128 regs, 32KB->64 regs + 1.3GB spill traffic),
// ignoring launch_bounds/waves_per_eu hints. The grid is 2 blocks/CU anyway (512 blocks
// / 256 CUs), so the pad costs NOTHING in real occupancy and buys back the registers.
struct SM {
    unsigned short Acat[GPB * KDIM];  // [16][512] bf16 bits, byte ^= (row&7)<<4
    float h[GPB * DIM];               // [16][256] fp32
    float pad[6144];                  // 24KB occupancy-shaping pad (never accessed)
};

// ---------------- prep: CSR offsets + W fragment-major bf16 + fused bias ------------
// Gate-column reorder: n = 128*(d>>5) + 32*gate + (d&31)  (gate order i,f,g,o).
// Wfrag layout: elem[((nfrag*16 + kstep)*64 + lane)*8 + j] = W[n=16*nfrag+(lane&15)][k=32*kstep+8*(lane>>4)+j]
// -> each MFMA B-fragment is one fully-coalesced 1KB wave load.
__global__ __launch_bounds__(256) void k_prep(const int* __restrict__ batch, int n_nodes,
        int* __restrict__ offs,
        const float* __restrict__ Wih, const float* __restrict__ Whh,
        const float* __restrict__ bih, const float* __restrict__ bhh,
        bf16* __restrict__ Wfrag, float* __restrict__ bsum) {
    const int idx = blockIdx.x * blockDim.x + threadIdx.x;
    if (idx < 64 * 16 * 64) {               // 65536 threads, one u16x8 each
        const int nfrag = idx >> 10;        // 0..63
        const int kstep = (idx >> 6) & 15;  // 0..15
        const int lane  = idx & 63;
        const int c  = nfrag * 16 + (lane & 15);        // gate-col n
        const int k0 = kstep * 32 + (lane >> 4) * 8;
        const int d  = ((c >> 7) << 5) | (c & 31);
        const int gt = (c >> 5) & 3;
        const int jsrc = gt * DIM + d;                  // source row in Wih/Whh
        u16x8 pk;
        #pragma unroll
        for (int j = 0; j < 8; ++j) {
            const int k = k0 + j;
            const float v = (k < DIM) ? Wih[(size_t)jsrc * DIM + k]
                                      : Whh[(size_t)jsrc * DIM + (k - DIM)];
            pk[j] = f2bf(v);
        }
        *(u16x8*)&Wfrag[(size_t)idx * 8] = pk;
    }
    if (idx < GDIM) {
        const int d  = ((idx >> 7) << 5) | (idx & 31);
        const int gt = (idx >> 5) & 3;
        const int jsrc = gt * DIM + d;
        bsum[idx] = bih[jsrc] + bhh[jsrc];
    }
    if (idx < n_nodes) {
        const int b  = batch[idx];
        const int bp = (idx == 0) ? -1 : batch[idx - 1];
        for (int g = bp + 1; g <= b; ++g) offs[g] = idx;
        if (idx == n_nodes - 1)
            for (int g = b + 1; g <= NG; ++g) offs[g] = n_nodes;
    }
}

// ---------------- attention phase (device fn, block-local, BATCHED) ----------------
// MODE 0 (iter 0): h == 0 -> every score is 0 -> e = 1 -> readout is the SEGMENT MEAN.
//   Pure stream: read fp32 x, accumulate, transcode fp16 copy. No dots/softmax/hreg.
//   (Bit-identical to the general path at h=0: al = e = exp(0) = 1, s = n.)
// MODE 1 (mid) / MODE 2 (last): fp16 rows, online softmax, batches of 4 rows per
//   32-lane half, software-pipelined one batch ahead (4 independent loads in flight).
//   x stays PACKED in curP between uses (re-unpacked at the racc update: 32 extra
//   v_cvt per batch buys back 32 VGPRs of liveness vs a cached xv[4][8]).
//   Invalid rows use clamped addresses and dt=-1e30 so e=0 contributes nothing.
// MODE 2 additionally writes the fp32 readout to out[:, 256:512].
template <int MODE>
__device__ __forceinline__ void att_phase(int w, int lane, int g0,
        const float* __restrict__ xf, unsigned short* __restrict__ xb,
        const int* __restrict__ offs, float* __restrict__ out,
        SM& sm, int nmax) {
    const int half = lane >> 5, hl = lane & 31;
    #pragma unroll 1
    for (int gi = 0; gi < GPW; ++gi) {
        const int gl = w * GPW + gi;
        const int g  = g0 + gl;
        const int start = offs[g], end = offs[g + 1];
        const int n  = end - start;
        const int nb = (n + 7) >> 3;   // batches of 8 rows (4 per half)
        float racc[8] = {0, 0, 0, 0, 0, 0, 0, 0};
        float s = 0.0f;

        if constexpr (MODE == 0) {
            // ---- segment mean + fp16 transcode ----
            float4 curA[4], curB[4];
            #pragma unroll
            for (int j = 0; j < 4; ++j) {
                const int r = start + half + 2 * j;
                const size_t ap = (size_t)min(r, nmax) * DIM + hl * 8;
                curA[j] = *(const float4*)&xf[ap];
                curB[j] = *(const float4*)&xf[ap + 4];
            }
            #pragma unroll 1
            for (int b = 0; b < nb; ++b) {
                float4 nxtA[4], nxtB[4];
                #pragma unroll
                for (int j = 0; j < 4; ++j) {
                    const int r = start + half + 2 * (4 * (b + 1) + j);
                    const size_t ap = (size_t)min(r, nmax) * DIM + hl * 8;
                    nxtA[j] = *(const float4*)&xf[ap];
                    nxtB[j] = *(const float4*)&xf[ap + 4];
                }
                #pragma unroll
                for (int j = 0; j < 4; ++j) {
                    const int r = start + half + 2 * (4 * b + j);
                    if (r < end) {
                        racc[0] += curA[j].x; racc[1] += curA[j].y;
                        racc[2] += curA[j].z; racc[3] += curA[j].w;
                        racc[4] += curB[j].x; racc[5] += curB[j].y;
                        racc[6] += curB[j].z; racc[7] += curB[j].w;
                        u16x8 st;
                        st[0] = f2h(curA[j].x); st[1] = f2h(curA[j].y);
                        st[2] = f2h(curA[j].z); st[3] = f2h(curA[j].w);
                        st[4] = f2h(curB[j].x); st[5] = f2h(curB[j].y);
                        st[6] = f2h(curB[j].z); st[7] = f2h(curB[j].w);
                        *(u16x8*)&xb[(size_t)r * DIM + hl * 8] = st;
                    }
                }
                #pragma unroll
                for (int j = 0; j < 4; ++j) { curA[j] = nxtA[j]; curB[j] = nxtB[j]; }
            }
            s = 0.0f;   // unused; inv computed from n below
        } else {
            float hreg[8];
            {
                const float4 a = *(const float4*)&sm.h[gl * DIM + hl * 8];
                const float4 b = *(const float4*)&sm.h[gl * DIM + hl * 8 + 4];
                hreg[0] = a.x; hreg[1] = a.y; hreg[2] = a.z; hreg[3] = a.w;
                hreg[4] = b.x; hreg[5] = b.y; hreg[6] = b.z; hreg[7] = b.w;
            }
            u16x8 curP[4];
            #pragma unroll
            for (int j = 0; j < 4; ++j) {
                const int r = start + half + 2 * j;
                curP[j] = *(const u16x8*)&xb[(size_t)min(r, nmax) * DIM + hl * 8];
            }
            float m = 0.0f;      // running max; init 0 == max(seg_max, 0) clamp
            #pragma unroll 1
            for (int b = 0; b < nb; ++b) {
                u16x8 nxtP[4];
                #pragma unroll
                for (int j = 0; j < 4; ++j) {
                    const int r = start + half + 2 * (4 * (b + 1) + j);
                    nxtP[j] = *(const u16x8*)&xb[(size_t)min(r, nmax) * DIM + hl * 8];
                }
                float dt[4];
                #pragma unroll
                for (int j = 0; j < 4; ++j) {
                    float d = 0.0f;
                    #pragma unroll
                    for (int i = 0; i < 8; ++i) d = fmaf(h2f(curP[j][i]), hreg[i], d);
                    dt[j] = d;
                }
                #pragma unroll
                for (int off = 16; off > 0; off >>= 1) {
                    #pragma unroll
                    for (int j = 0; j < 4; ++j) dt[j] += __shfl_xor(dt[j], off);
                }
                #pragma unroll
                for (int j = 0; j < 4; ++j) {
                    const int r = start + half + 2 * (4 * b + j);
                    const float d  = (r < end) ? dt[j] : -1e30f;
                    const float mn = fmaxf(m, d);
                    const float al = __expf(m - mn);
                    const float e  = __expf(d - mn);
                    s = s * al + e;
                    #pragma unroll
                    for (int i = 0; i < 8; ++i)
                        racc[i] = fmaf(racc[i], al, e * h2f(curP[j][i]));
                    m = mn;
                }
                #pragma unroll
                for (int j = 0; j < 4; ++j) curP[j] = nxtP[j];
            }
            // merge the two halves (online-softmax merge)
            const float mo = __shfl_xor(m, 32);
            const float M  = fmaxf(m, mo);
            const float am = __expf(m - M);
            s *= am;
            #pragma unroll
            for (int j = 0; j < 8; ++j) racc[j] *= am;
        }

        // merge halves (MODE 0: am == 1 path is just the adds below)
        if constexpr (MODE != 0) s += __shfl_xor(s, 32);
        #pragma unroll
        for (int j = 0; j < 8; ++j) racc[j] += __shfl_xor(racc[j], 32);
        const float inv = (MODE == 0) ? 1.0f / ((float)n + 1e-8f)
                                      : 1.0f / (s + 1e-8f);
        if (half == 0) {          // bf16 readout into swizzled A (k = 0..255)
            u16x8 ob;
            #pragma unroll
            for (int j = 0; j < 8; ++j) ob[j] = f2bf(racc[j] * inv);
            unsigned off = (unsigned)(gl * 1024 + hl * 16);
            off ^= (unsigned)((gl & 7) << 4);
            *(u16x8*)((char*)sm.Acat + off) = ob;
        } else if (MODE == 2) {   // fp32 readout straight into out[:, 256:512]
            float o[8];
            #pragma unroll
            for (int j = 0; j < 8; ++j) o[j] = racc[j] * inv;
            *(float4*)&out[(size_t)g * KDIM + DIM + hl * 8]     = make_float4(o[0], o[1], o[2], o[3]);
            *(float4*)&out[(size_t)g * KDIM + DIM + hl * 8 + 4] = make_float4(o[4], o[5], o[6], o[7]);
        }
    }
}

// ---------------- fully fused kernel: 6x (att -> GEMM -> cell), block-local ----------------
// Block owns 16 graphs. 56KB static LDS (32 real + 24 pad) -> compiler targets 2 blocks/CU
// = 4 waves/EU -> 128-VGPR budget; worst-phase live set ~90-110 regs -> no spill.
// GEMM: per wave a 16x128 output tile: A (16x512) from swizzled LDS, B streamed from
// global Wfrag with a split register double-buffer (bA/bB, 4 loads in flight under the
// 4 MFMAs of the other half).
__global__ __launch_bounds__(NTHR)
__attribute__((amdgpu_waves_per_eu(4, 4)))
void k_fused(const float* __restrict__ xf,
        unsigned short* __restrict__ xb, const int* __restrict__ offs,
        const bf16* __restrict__ Wfrag, const float* __restrict__ bsum,
        float* __restrict__ out, int n_nodes) {
    __shared__ SM sm;
    const int tid  = threadIdx.x;
    const int w    = tid >> 6, lane = tid & 63;
    const int g0   = blockIdx.x * GPB;
    const int nmax = n_nodes - 1;

    for (int i = tid; i < GPB * KDIM; i += NTHR) sm.Acat[i] = 0;   // h-region must be bf16 zero
    for (int i = tid; i < GPB * DIM;  i += NTHR) sm.h[i] = 0.0f;

    float c_[2][4] = {};              // persistent cell state: 8 regs/lane
    float bv[8];
    #pragma unroll
    for (int nf = 0; nf < 8; ++nf) bv[nf] = bsum[w * 128 + nf * 16 + (lane & 15)];

    __syncthreads();

    const bf16* wb = Wfrag + (size_t)w * 65536 + (size_t)lane * 8;

    for (int it = 0; it < N_ITERS; ++it) {
        // ---- attention (reads sm.h, writes sm.Acat readout region) ----
        if (it == 0)                att_phase<0>(w, lane, g0, xf, xb, offs, out, sm, nmax);
        else if (it < N_ITERS - 1)  att_phase<1>(w, lane, g0, xf, xb, offs, out, sm, nmax);
        else                        att_phase<2>(w, lane, g0, xf, xb, offs, out, sm, nmax);
        __syncthreads();

        // ---- GEMM: gates(16x1024) = A(16x512) @ W^T, wave w -> cols [128w, 128w+128) ----
        f32x4 acc[8] = {};
        const int r0 = lane & 15;
        bf16x8 bA[4], bB[4];
        #pragma unroll
        for (int q = 0; q < 4; ++q) bA[q] = *(const bf16x8*)&wb[(size_t)q * 8192];
        #pragma unroll
        for (int q = 0; q < 4; ++q) bB[q] = *(const bf16x8*)&wb[(size_t)(q + 4) * 8192];
        #pragma unroll
        for (int kstep = 0; kstep < 16; ++kstep) {
            const unsigned o0 = (unsigned)(r0 * 1024 + kstep * 64 + (lane >> 4) * 16)
                              ^ (unsigned)((r0 & 7) << 4);
            const bf16x8 a = *(const bf16x8*)((const char*)sm.Acat + o0);
            const int kn = ((kstep + 1) & 15) * 512;   // wraps at the end; harmless
            #pragma unroll
            for (int q = 0; q < 4; ++q)
                acc[q] = __builtin_amdgcn_mfma_f32_16x16x32_bf16(a, bA[q], acc[q], 0, 0, 0);
            #pragma unroll
            for (int q = 0; q < 4; ++q) bA[q] = *(const bf16x8*)&wb[(size_t)q * 8192 + kn];
            #pragma unroll
            for (int q = 0; q < 4; ++q)
                acc[4 + q] = __builtin_amdgcn_mfma_f32_16x16x32_bf16(a, bB[q], acc[4 + q], 0, 0, 0);
            #pragma unroll
            for (int q = 0; q < 4; ++q) bB[q] = *(const bf16x8*)&wb[(size_t)(q + 4) * 8192 + kn];
        }
        __syncthreads();   // all waves done reading sm.Acat/sm.h before cell overwrites

        // ---- LSTM cell: lane-local gates (nf = 2*gate + dhi), update c, write h ----
        #pragma unroll
        for (int dhi = 0; dhi < 2; ++dhi) {
            const int d = w * 32 + dhi * 16 + (lane & 15);
            #pragma unroll
            for (int rr = 0; rr < 4; ++rr) {
                const int row = (lane >> 4) * 4 + rr;
                const float gi_ = acc[0 + dhi][rr] + bv[0 + dhi];
                const float gf_ = acc[2 + dhi][rr] + bv[2 + dhi];
                const float gg_ = acc[4 + dhi][rr] + bv[4 + dhi];
                const float go_ = acc[6 + dhi][rr] + bv[6 + dhi];
                const float cn = fast_sigmoid(gf_) * c_[dhi][rr]
                               + fast_sigmoid(gi_) * fast_tanh(gg_);
                const float hn = fast_sigmoid(go_) * fast_tanh(cn);
                c_[dhi][rr] = cn;
                sm.h[row * DIM + d] = hn;
                unsigned ho = (unsigned)(row * 1024 + (DIM + d) * 2)
                            ^ (unsigned)((row & 7) << 4);
                *(unsigned short*)((char*)sm.Acat + ho) = f2bf(hn);
            }
        }
        __syncthreads();
    }

    // final h (fp32, from LDS) -> out[:, 0:256], coalesced float4
    for (int i = tid; i < GPB * 64; i += NTHR) {
        const int row = i >> 6;
        const int dq  = (i & 63) << 2;
        *(float4*)&out[(size_t)(g0 + row) * KDIM + dq] = *(const float4*)&sm.h[row * DIM + dq];
    }
}

extern "C" void kernel_launch(void* const* d_in, const int* in_sizes, int n_in,
                              void* d_out, int out_size, void* d_ws, size_t ws_size,
                              hipStream_t stream) {
    const float* x     = (const float*)d_in[0];
    const int*   batch = (const int*)d_in[1];
    // d_in[2] = n_graphs scalar (8192, hardcoded)
    const float* Wih   = (const float*)d_in[3];
    const float* Whh   = (const float*)d_in[4];
    const float* bih   = (const float*)d_in[5];
    const float* bhh   = (const float*)d_in[6];
    const int n_nodes  = in_sizes[0] / DIM;
    float* out = (float*)d_out;

    char* ws = (char*)d_ws;
    size_t off = 0;
    auto alloc = [&](size_t bytes) -> void* {
        off = (off + 255) & ~(size_t)255;
        void* p = ws + off;
        off += bytes;
        return p;
    };
    int*   offs  = (int*)  alloc((size_t)(NG + 1) * sizeof(int));
    bf16*  Wfrag = (bf16*) alloc((size_t)GDIM * KDIM * sizeof(bf16));
    float* bsum  = (float*)alloc((size_t)GDIM * sizeof(float));
    unsigned short* xb = (unsigned short*)alloc((size_t)n_nodes * DIM * sizeof(unsigned short));
    (void)ws_size; (void)n_in; (void)out_size;

    const int cover = (n_nodes > 64 * 16 * 64) ? n_nodes : 64 * 16 * 64;
    const int pb = (cover + 255) / 256;

    k_prep<<<pb, 256, 0, stream>>>(batch, n_nodes, offs, Wih, Whh, bih, bhh, Wfrag, bsum);
    k_fused<<<NBLK, NTHR, 0, stream>>>(x, xb, offs, Wfrag, bsum, out, n_nodes);
}

// Round 7
// 905.702 us; speedup vs baseline: 1.3425x; 1.3425x over previous
//
#include <hip/hip_runtime.h>
#include <hip/hip_bf16.h>
#include <hip/hip_fp16.h>
#include <stdint.h>

#define DIM 256
#define NG 8192
#define KDIM 512      // 2*DIM (concat [readout | h])
#define GDIM 1024     // 4*DIM gates
#define N_ITERS 6
#define GPB 32        // graphs per block (R3 shape: 64 KB LDS, 128-VGPR tier)
#define NBLK (NG / GPB)   // 256 blocks = 1 per CU
#define NTHR 512          // 8 waves
#define GPW 4             // graphs per wave in att

typedef __hip_bfloat16 bf16;
typedef __attribute__((ext_vector_type(8))) short bf16x8;
typedef __attribute__((ext_vector_type(4))) float f32x4;
typedef __attribute__((ext_vector_type(8))) unsigned short u16x8;

// ---------------- helpers --------------
__device__ __forceinline__ float fast_sigmoid(float v) {
    return 1.0f / (1.0f + __expf(-v));
}
__device__ __forceinline__ float fast_tanh(float v) {
    float e = __expf(2.0f * v);
    return (e - 1.0f) / (e + 1.0f);
}
__device__ __forceinline__ unsigned short f2bf(float v) {
    __hip_bfloat16 t = __float2bfloat16(v);
    unsigned short u; __builtin_memcpy(&u, &t, 2); return u;
}
__device__ __forceinline__ unsigned short f2h(float v) {
    __half t = __float2half_rn(v);
    unsigned short u; __builtin_memcpy(&u, &t, 2); return u;
}
__device__ __forceinline__ float h2f(unsigned short u) {
    __half t; __builtin_memcpy(&t, &u, 2);
    return __half2float(t);
}

// Block-local persistent state: A=[readout|h] bf16 (XOR-swizzled rows) + h fp32.
// 32KB + 32KB = 64KB static LDS. This is the R1-R3 shape that measurably lands the
// allocator on the 128-VGPR tier (R4-R6's 32KB shape landed on 64 + ~1.85GB spill).
struct SM {
    unsigned short Acat[GPB * KDIM];  // [32][512] bf16 bits, byte ^= (row&7)<<4
    float h[GPB * DIM];               // [32][256] fp32
};

// ---------------- prep: CSR offsets + W fragment-major bf16 + fused bias ------------
// Gate-column reorder: n = 128*(d>>5) + 32*gate + (d&31)  (gate order i,f,g,o).
// Wfrag layout: elem[((nfrag*16 + kstep)*64 + lane)*8 + j] = W[n=16*nfrag+(lane&15)][k=32*kstep+8*(lane>>4)+j]
// -> each MFMA B-fragment is one fully-coalesced 1KB wave load.
__global__ __launch_bounds__(256) void k_prep(const int* __restrict__ batch, int n_nodes,
        int* __restrict__ offs,
        const float* __restrict__ Wih, const float* __restrict__ Whh,
        const float* __restrict__ bih, const float* __restrict__ bhh,
        bf16* __restrict__ Wfrag, float* __restrict__ bsum) {
    const int idx = blockIdx.x * blockDim.x + threadIdx.x;
    if (idx < 64 * 16 * 64) {               // 65536 threads, one u16x8 each
        const int nfrag = idx >> 10;        // 0..63
        const int kstep = (idx >> 6) & 15;  // 0..15
        const int lane  = idx & 63;
        const int c  = nfrag * 16 + (lane & 15);        // gate-col n
        const int k0 = kstep * 32 + (lane >> 4) * 8;
        const int d  = ((c >> 7) << 5) | (c & 31);
        const int gt = (c >> 5) & 3;
        const int jsrc = gt * DIM + d;                  // source row in Wih/Whh
        u16x8 pk;
        #pragma unroll
        for (int j = 0; j < 8; ++j) {
            const int k = k0 + j;
            const float v = (k < DIM) ? Wih[(size_t)jsrc * DIM + k]
                                      : Whh[(size_t)jsrc * DIM + (k - DIM)];
            pk[j] = f2bf(v);
        }
        *(u16x8*)&Wfrag[(size_t)idx * 8] = pk;
    }
    if (idx < GDIM) {
        const int d  = ((idx >> 7) << 5) | (idx & 31);
        const int gt = (idx >> 5) & 3;
        const int jsrc = gt * DIM + d;
        bsum[idx] = bih[jsrc] + bhh[jsrc];
    }
    if (idx < n_nodes) {
        const int b  = batch[idx];
        const int bp = (idx == 0) ? -1 : batch[idx - 1];
        for (int g = bp + 1; g <= b; ++g) offs[g] = idx;
        if (idx == n_nodes - 1)
            for (int g = b + 1; g <= NG; ++g) offs[g] = n_nodes;
    }
}

// ---------------- attention phase (device fn, block-local, BATCHED) ----------------
// MODE 0 (iter 0): h == 0 -> every score is 0 -> e = 1 -> readout is the SEGMENT MEAN.
//   Pure stream: read fp32 x, accumulate, transcode fp16 copy. (Bit-identical to the
//   general path at h=0: al = e = exp(0) = 1, s = n.)
// MODE 1 (mid) / MODE 2 (last): fp16 rows, online softmax, batches of 4 rows per
//   32-lane half, software-pipelined one batch ahead (4 independent loads in flight).
//   x stays PACKED in curP between uses (re-unpacked at the racc update: trades 32
//   v_cvt per batch for 32 VGPRs of liveness). Invalid rows use clamped addresses and
//   dt=-1e30 so e=0 contributes nothing.
// MODE 2 additionally writes the fp32 readout to out[:, 256:512].
template <int MODE>
__device__ __forceinline__ void att_phase(int w, int lane, int g0,
        const float* __restrict__ xf, unsigned short* __restrict__ xb,
        const int* __restrict__ offs, float* __restrict__ out,
        SM& sm, int nmax) {
    const int half = lane >> 5, hl = lane & 31;
    #pragma unroll 1
    for (int gi = 0; gi < GPW; ++gi) {
        const int gl = w * GPW + gi;
        const int g  = g0 + gl;
        const int start = offs[g], end = offs[g + 1];
        const int n  = end - start;
        const int nb = (n + 7) >> 3;   // batches of 8 rows (4 per half)
        float racc[8] = {0, 0, 0, 0, 0, 0, 0, 0};
        float s = 0.0f;

        if constexpr (MODE == 0) {
            // ---- segment mean + fp16 transcode ----
            float4 curA[4], curB[4];
            #pragma unroll
            for (int j = 0; j < 4; ++j) {
                const int r = start + half + 2 * j;
                const size_t ap = (size_t)min(r, nmax) * DIM + hl * 8;
                curA[j] = *(const float4*)&xf[ap];
                curB[j] = *(const float4*)&xf[ap + 4];
            }
            #pragma unroll 1
            for (int b = 0; b < nb; ++b) {
                float4 nxtA[4], nxtB[4];
                #pragma unroll
                for (int j = 0; j < 4; ++j) {
                    const int r = start + half + 2 * (4 * (b + 1) + j);
                    const size_t ap = (size_t)min(r, nmax) * DIM + hl * 8;
                    nxtA[j] = *(const float4*)&xf[ap];
                    nxtB[j] = *(const float4*)&xf[ap + 4];
                }
                #pragma unroll
                for (int j = 0; j < 4; ++j) {
                    const int r = start + half + 2 * (4 * b + j);
                    if (r < end) {
                        racc[0] += curA[j].x; racc[1] += curA[j].y;
                        racc[2] += curA[j].z; racc[3] += curA[j].w;
                        racc[4] += curB[j].x; racc[5] += curB[j].y;
                        racc[6] += curB[j].z; racc[7] += curB[j].w;
                        u16x8 st;
                        st[0] = f2h(curA[j].x); st[1] = f2h(curA[j].y);
                        st[2] = f2h(curA[j].z); st[3] = f2h(curA[j].w);
                        st[4] = f2h(curB[j].x); st[5] = f2h(curB[j].y);
                        st[6] = f2h(curB[j].z); st[7] = f2h(curB[j].w);
                        *(u16x8*)&xb[(size_t)r * DIM + hl * 8] = st;
                    }
                }
                #pragma unroll
                for (int j = 0; j < 4; ++j) { curA[j] = nxtA[j]; curB[j] = nxtB[j]; }
            }
            s = 0.0f;   // unused; inv computed from n below
        } else {
            float hreg[8];
            {
                const float4 a = *(const float4*)&sm.h[gl * DIM + hl * 8];
                const float4 b = *(const float4*)&sm.h[gl * DIM + hl * 8 + 4];
                hreg[0] = a.x; hreg[1] = a.y; hreg[2] = a.z; hreg[3] = a.w;
                hreg[4] = b.x; hreg[5] = b.y; hreg[6] = b.z; hreg[7] = b.w;
            }
            u16x8 curP[4];
            #pragma unroll
            for (int j = 0; j < 4; ++j) {
                const int r = start + half + 2 * j;
                curP[j] = *(const u16x8*)&xb[(size_t)min(r, nmax) * DIM + hl * 8];
            }
            float m = 0.0f;      // running max; init 0 == max(seg_max, 0) clamp
            #pragma unroll 1
            for (int b = 0; b < nb; ++b) {
                u16x8 nxtP[4];
                #pragma unroll
                for (int j = 0; j < 4; ++j) {
                    const int r = start + half + 2 * (4 * (b + 1) + j);
                    nxtP[j] = *(const u16x8*)&xb[(size_t)min(r, nmax) * DIM + hl * 8];
                }
                float dt[4];
                #pragma unroll
                for (int j = 0; j < 4; ++j) {
                    float d = 0.0f;
                    #pragma unroll
                    for (int i = 0; i < 8; ++i) d = fmaf(h2f(curP[j][i]), hreg[i], d);
                    dt[j] = d;
                }
                #pragma unroll
                for (int off = 16; off > 0; off >>= 1) {
                    #pragma unroll
                    for (int j = 0; j < 4; ++j) dt[j] += __shfl_xor(dt[j], off);
                }
                #pragma unroll
                for (int j = 0; j < 4; ++j) {
                    const int r = start + half + 2 * (4 * b + j);
                    const float d  = (r < end) ? dt[j] : -1e30f;
                    const float mn = fmaxf(m, d);
                    const float al = __expf(m - mn);
                    const float e  = __expf(d - mn);
                    s = s * al + e;
                    #pragma unroll
                    for (int i = 0; i < 8; ++i)
                        racc[i] = fmaf(racc[i], al, e * h2f(curP[j][i]));
                    m = mn;
                }
                #pragma unroll
                for (int j = 0; j < 4; ++j) curP[j] = nxtP[j];
            }
            // merge the two halves (online-softmax merge)
            const float mo = __shfl_xor(m, 32);
            const float M  = fmaxf(m, mo);
            const float am = __expf(m - M);
            s *= am;
            #pragma unroll
            for (int j = 0; j < 8; ++j) racc[j] *= am;
        }

        // merge halves (MODE 0: am == 1 path is just the adds below)
        if constexpr (MODE != 0) s += __shfl_xor(s, 32);
        #pragma unroll
        for (int j = 0; j < 8; ++j) racc[j] += __shfl_xor(racc[j], 32);
        const float inv = (MODE == 0) ? 1.0f / ((float)n + 1e-8f)
                                      : 1.0f / (s + 1e-8f);
        if (half == 0) {          // bf16 readout into swizzled A (k = 0..255)
            u16x8 ob;
            #pragma unroll
            for (int j = 0; j < 8; ++j) ob[j] = f2bf(racc[j] * inv);
            unsigned off = (unsigned)(gl * 1024 + hl * 16);
            off ^= (unsigned)((gl & 7) << 4);
            *(u16x8*)((char*)sm.Acat + off) = ob;
        } else if (MODE == 2) {   // fp32 readout straight into out[:, 256:512]
            float o[8];
            #pragma unroll
            for (int j = 0; j < 8; ++j) o[j] = racc[j] * inv;
            *(float4*)&out[(size_t)g * KDIM + DIM + hl * 8]     = make_float4(o[0], o[1], o[2], o[3]);
            *(float4*)&out[(size_t)g * KDIM + DIM + hl * 8 + 4] = make_float4(o[4], o[5], o[6], o[7]);
        }
    }
}

// ---------------- fully fused kernel: 6x (att -> GEMM -> cell), block-local ----------------
// R3 shape (GPB=32, 64KB LDS, launch_bounds(512,2)) -- the config the allocator measurably
// gives 128 VGPRs -- with the GEMM's register demand cut to FIT that budget:
// B-fragments single-buffered in 2-frag chunks (live B = 8-16 regs vs R3's 64-reg double
// buffer, whose overflow was R3's ~550MB scratch traffic). Live set ~118 <= 128.
__global__ __launch_bounds__(NTHR, 2) void k_fused(const float* __restrict__ xf,
        unsigned short* __restrict__ xb, const int* __restrict__ offs,
        const bf16* __restrict__ Wfrag, const float* __restrict__ bsum,
        float* __restrict__ out, int n_nodes) {
    __shared__ SM sm;
    const int tid  = threadIdx.x;
    const int w    = tid >> 6, lane = tid & 63;
    const int g0   = blockIdx.x * GPB;
    const int nmax = n_nodes - 1;

    for (int i = tid; i < GPB * KDIM; i += NTHR) sm.Acat[i] = 0;   // h-region must be bf16 zero
    for (int i = tid; i < GPB * DIM;  i += NTHR) sm.h[i] = 0.0f;

    float c_[2][2][4] = {};           // persistent cell state: 16 regs/lane
    float bv[8];
    #pragma unroll
    for (int nf = 0; nf < 8; ++nf) bv[nf] = bsum[w * 128 + nf * 16 + (lane & 15)];

    __syncthreads();

    const bf16* wb = Wfrag + (size_t)w * 65536 + (size_t)lane * 8;

    for (int it = 0; it < N_ITERS; ++it) {
        // ---- attention (reads sm.h, writes sm.Acat readout region) ----
        if (it == 0)                att_phase<0>(w, lane, g0, xf, xb, offs, out, sm, nmax);
        else if (it < N_ITERS - 1)  att_phase<1>(w, lane, g0, xf, xb, offs, out, sm, nmax);
        else                        att_phase<2>(w, lane, g0, xf, xb, offs, out, sm, nmax);
        __syncthreads();

        // ---- GEMM: gates(32x1024) = A(32x512) @ W^T, wave w -> cols [128w, 128w+128) ----
        f32x4 acc[2][8] = {};
        const int r0 = lane & 15;
        #pragma unroll
        for (int kstep = 0; kstep < 16; ++kstep) {
            const unsigned o0 = (unsigned)(r0 * 1024 + kstep * 64 + (lane >> 4) * 16)
                              ^ (unsigned)((r0 & 7) << 4);
            const unsigned o1 = o0 + 16 * 1024;   // row+16 has same (row&7) -> same XOR
            const bf16x8 a0 = *(const bf16x8*)((const char*)sm.Acat + o0);
            const bf16x8 a1 = *(const bf16x8*)((const char*)sm.Acat + o1);
            // B single-buffered in 2-fragment chunks: live B stays at 8-16 VGPRs.
            #pragma unroll
            for (int q = 0; q < 4; ++q) {
                const bf16x8 b0 = *(const bf16x8*)&wb[(size_t)(2 * q)     * 8192 + kstep * 512];
                const bf16x8 b1 = *(const bf16x8*)&wb[(size_t)(2 * q + 1) * 8192 + kstep * 512];
                acc[0][2 * q]     = __builtin_amdgcn_mfma_f32_16x16x32_bf16(a0, b0, acc[0][2 * q],     0, 0, 0);
                acc[1][2 * q]     = __builtin_amdgcn_mfma_f32_16x16x32_bf16(a1, b0, acc[1][2 * q],     0, 0, 0);
                acc[0][2 * q + 1] = __builtin_amdgcn_mfma_f32_16x16x32_bf16(a0, b1, acc[0][2 * q + 1], 0, 0, 0);
                acc[1][2 * q + 1] = __builtin_amdgcn_mfma_f32_16x16x32_bf16(a1, b1, acc[1][2 * q + 1], 0, 0, 0);
            }
        }
        __syncthreads();   // all waves done reading sm.Acat/sm.h before cell overwrites

        // ---- LSTM cell: lane-local gates (nf = 2*gate + dhi), update c, write h ----
        #pragma unroll
        for (int mf = 0; mf < 2; ++mf) {
            #pragma unroll
            for (int dhi = 0; dhi < 2; ++dhi) {
                const int d = w * 32 + dhi * 16 + (lane & 15);
                #pragma unroll
                for (int rr = 0; rr < 4; ++rr) {
                    const int row = mf * 16 + (lane >> 4) * 4 + rr;
                    const float gi_ = acc[mf][0 + dhi][rr] + bv[0 + dhi];
                    const float gf_ = acc[mf][2 + dhi][rr] + bv[2 + dhi];
                    const float gg_ = acc[mf][4 + dhi][rr] + bv[4 + dhi];
                    const float go_ = acc[mf][6 + dhi][rr] + bv[6 + dhi];
                    const float cn = fast_sigmoid(gf_) * c_[mf][dhi][rr]
                                   + fast_sigmoid(gi_) * fast_tanh(gg_);
                    const float hn = fast_sigmoid(go_) * fast_tanh(cn);
                    c_[mf][dhi][rr] = cn;
                    sm.h[row * DIM + d] = hn;
                    unsigned ho = (unsigned)(row * 1024 + (DIM + d) * 2)
                                ^ (unsigned)((row & 7) << 4);
                    *(unsigned short*)((char*)sm.Acat + ho) = f2bf(hn);
                }
            }
        }
        __syncthreads();
    }

    // final h (fp32, from LDS) -> out[:, 0:256], coalesced float4
    for (int i = tid; i < GPB * 64; i += NTHR) {
        const int row = i >> 6;
        const int dq  = (i & 63) << 2;
        *(float4*)&out[(size_t)(g0 + row) * KDIM + dq] = *(const float4*)&sm.h[row * DIM + dq];
    }
}

extern "C" void kernel_launch(void* const* d_in, const int* in_sizes, int n_in,
                              void* d_out, int out_size, void* d_ws, size_t ws_size,
                              hipStream_t stream) {
    const float* x     = (const float*)d_in[0];
    const int*   batch = (const int*)d_in[1];
    // d_in[2] = n_graphs scalar (8192, hardcoded)
    const float* Wih   = (const float*)d_in[3];
    const float* Whh   = (const float*)d_in[4];
    const float* bih   = (const float*)d_in[5];
    const float* bhh   = (const float*)d_in[6];
    const int n_nodes  = in_sizes[0] / DIM;
    float* out = (float*)d_out;

    char* ws = (char*)d_ws;
    size_t off = 0;
    auto alloc = [&](size_t bytes) -> void* {
        off = (off + 255) & ~(size_t)255;
        void* p = ws + off;
        off += bytes;
        return p;
    };
    int*   offs  = (int*)  alloc((size_t)(NG + 1) * sizeof(int));
    bf16*  Wfrag = (bf16*) alloc((size_t)GDIM * KDIM * sizeof(bf16));
    float* bsum  = (float*)alloc((size_t)GDIM * sizeof(float));
    unsigned short* xb = (unsigned short*)alloc((size_t)n_nodes * DIM * sizeof(unsigned short));
    (void)ws_size; (void)n_in; (void)out_size;

    const int cover = (n_nodes > 64 * 16 * 64) ? n_nodes : 64 * 16 * 64;
    const int pb = (cover + 255) / 256;

    k_prep<<<pb, 256, 0, stream>>>(batch, n_nodes, offs, Wih, Whh, bih, bhh, Wfrag, bsum);
    k_fused<<<NBLK, NTHR, 0, stream>>>(x, xb, offs, Wfrag, bsum, out, n_nodes);
}